// Round 8
// baseline (187.424 us; speedup 1.0000x reference)
//
#include <hip/hip_runtime.h>
#include <hip/hip_bf16.h>
#include <math.h>

#define NSEQ 26
#define NSUP 25
#define LSEQ 46
#define DJ 90
#define H1 180
#define DIN 256
#define TT 1035
#define TTP 1056     // padded to 33*32
#define DOUT 128
#define WAY 5
#define SHOT 5
#define LNB 32       // logits partial blocks per class
#define SQRT_SCALE 0.29730177875068026f   // (1/sqrt(128))^0.5, folded into K (Q and K both)

typedef __attribute__((ext_vector_type(8))) short short8;
typedef __attribute__((ext_vector_type(4))) float f32x4;

__device__ __forceinline__ ushort f2bf(float x) {
    __hip_bfloat16 h = __float2bfloat16(x);
    return *reinterpret_cast<ushort*>(&h);
}

// ---------------- kernel 1: MLP (two relu layers) + positional encoding ----------------
__global__ void mlp_pe_kernel(const float* __restrict__ ss, const float* __restrict__ qsk,
                              const float* __restrict__ w1, const float* __restrict__ b1,
                              const float* __restrict__ w2, const float* __restrict__ b2,
                              float* __restrict__ feat) {
    __shared__ float xs[DJ];
    __shared__ float hs[H1];
    int r = blockIdx.x;
    int seq = r / LSEQ, l = r % LSEQ;
    const float* x = (seq < NSUP) ? (ss + (size_t)(seq * LSEQ + l) * DJ)
                                  : (qsk + (size_t)l * DJ);
    int tid = threadIdx.x;
    if (tid < DJ) xs[tid] = x[tid];
    __syncthreads();
    if (tid < H1) {
        float a = b1[tid];
        for (int k = 0; k < DJ; ++k) a += xs[k] * w1[k * H1 + tid];
        hs[tid] = fmaxf(a, 0.f);
    }
    __syncthreads();
    int d = tid;  // 0..255
    float a = b2[d];
    for (int k = 0; k < H1; ++k) a += hs[k] * w2[k * DIN + d];
    a = fmaxf(a, 0.f);
    int p2 = d & ~1;
    float freq = expf((float)p2 * (-9.210340371976184f / 256.0f));
    float ang = (float)l * freq;
    a += ((d & 1) ? cosf(ang) : sinf(ang)) * 0.1f;
    feat[(size_t)r * DIN + d] = a;
}

// ---------------- kernel 2: per-frame half projections (factorized tuple GEMM) ----------------
__global__ void proj_kernel(const float* __restrict__ feat,
                            const float* __restrict__ kw, const float* __restrict__ vw,
                            float* __restrict__ kp1, float* __restrict__ kp2,
                            float* __restrict__ vp1, float* __restrict__ vp2) {
    __shared__ float fs[DIN];
    int r = blockIdx.x, d = threadIdx.x;  // 128 threads
    fs[d] = feat[(size_t)r * DIN + d];
    fs[d + 128] = feat[(size_t)r * DIN + d + 128];
    __syncthreads();
    float a1 = 0.f, a2 = 0.f, a3 = 0.f, a4 = 0.f;
    for (int k = 0; k < DIN; ++k) {
        float f = fs[k];
        a1 += f * kw[k * DOUT + d];
        a2 += f * kw[(k + DIN) * DOUT + d];
        a3 += f * vw[k * DOUT + d];
        a4 += f * vw[(k + DIN) * DOUT + d];
    }
    size_t o = (size_t)r * DOUT + d;
    kp1[o] = a1; kp2[o] = a2; vp1[o] = a3; vp2[o] = a4;
}

// ---------------- kernel 3: tuple gather + bias + LayerNorm -> Kbf(bf16, pre-scaled), V(f32) ----------------
__global__ void kv_kernel(const float* __restrict__ kp1, const float* __restrict__ kp2,
                          const float* __restrict__ vp1, const float* __restrict__ vp2,
                          const float* __restrict__ kb, const float* __restrict__ vb,
                          const float* __restrict__ lg, const float* __restrict__ lb,
                          ushort* __restrict__ Kbf, float* __restrict__ V) {
    int b = blockIdx.x;
    int s = b / TT, t = b % TT;
    int i = 0, rem = t;
    while (rem >= (LSEQ - 1 - i)) { rem -= (LSEQ - 1 - i); ++i; }
    int j = i + 1 + rem;
    int d = threadIdx.x;  // 128 threads
    size_t fi = (size_t)(s * LSEQ + i) * DOUT + d;
    size_t fj = (size_t)(s * LSEQ + j) * DOUT + d;
    float kv = kp1[fi] + kp2[fj] + kb[d];
    float vv = vp1[fi] + vp2[fj] + vb[d];
    float sum = kv, sq = kv * kv;
    for (int off = 32; off >= 1; off >>= 1) {
        sum += __shfl_down(sum, off);
        sq  += __shfl_down(sq, off);
    }
    __shared__ float red[4];
    int wid = d >> 6, lane = d & 63;
    if (lane == 0) { red[wid * 2] = sum; red[wid * 2 + 1] = sq; }
    __syncthreads();
    sum = red[0] + red[2]; sq = red[1] + red[3];
    float m = sum * (1.f / DOUT);
    float var = sq * (1.f / DOUT) - m * m;
    float rs = rsqrtf(var + 1e-5f);
    float kn = ((kv - m) * rs * lg[d] + lb[d]) * SQRT_SCALE;
    Kbf[(size_t)s * TTP * DOUT + (size_t)t * DOUT + d] = f2bf(kn);
    V[((size_t)s * TT + t) * DOUT + d] = vv;
}

// ---------------- kernel 3b: V -> bf16 transpose  VbfT[p][d][t] ----------------
__global__ void vtrans_kernel(const float* __restrict__ V, ushort* __restrict__ VbfT) {
    __shared__ float tile[32][33];
    int p = blockIdx.z;
    int t0 = blockIdx.x * 32, d0 = blockIdx.y * 32;
    int tx = threadIdx.x & 31, ty = threadIdx.x >> 5;  // 256 thr: ty 0..7
    for (int i = ty; i < 32; i += 8) {
        int t = t0 + i;
        tile[i][tx] = (t < TT) ? V[((size_t)p * TT + t) * DOUT + d0 + tx] : 0.f;
    }
    __syncthreads();
    for (int i = ty; i < 32; i += 8) {
        int d = d0 + i;
        VbfT[((size_t)p * DOUT + d) * TTP + t0 + tx] = f2bf(tile[tx][i]);
    }
}

// ---------------- kernel 4: split-K MFMA flash attention, swapped QK^T ----------------
// mfma(K, Q) puts scores as C[key][q] with q = lane&15 -> softmax is
// lane-local over 8 regs + 2 shfl_xor (was 4 rows x 8 shfls = 32/tile).
// 4 waves split the 33 key-tiles (no in-loop barriers); (m,l,O) merged
// in a 2-round LDS epilogue. No min-waves bound (round-6 spill lesson).
__global__ __launch_bounds__(256) void attn_mfma_kernel(
        const ushort* __restrict__ Kbf, const ushort* __restrict__ VbfT,
        float* __restrict__ Obuf) {
    __shared__ __align__(16) ushort Plds[4][2][16][40];  // per-wave, dbuf by tile parity
    __shared__ float Ocomb[4][16][66];                    // 2-round combine, padded rows
    __shared__ float mstats[4][16][2];

    // bijective XCD-chunk swizzle (nwg=1625, nwg%8=1)
    const int nwg = 65 * NSUP;
    int orig = blockIdx.x;
    int cq = nwg >> 3, cr = nwg & 7;           // 203, 1
    int xcd = orig & 7, sub = orig >> 3;
    int wg = (xcd < cr ? xcd * (cq + 1) : cr * (cq + 1) + (xcd - cr) * cq) + sub;
    int p = wg / 65;                            // support pair 0..24
    int q0 = (wg % 65) * 16;

    int tid = threadIdx.x;
    int wid = tid >> 6;
    int lane = tid & 63;
    int g = lane >> 4, r16 = lane & 15;

    const ushort* Kq = Kbf + (size_t)NSUP * TTP * DOUT;   // query rows
    short8 qf[4];
    int qrow = q0 + r16;
    #pragma unroll
    for (int kc = 0; kc < 4; ++kc)
        qf[kc] = *(const short8*)(Kq + (size_t)qrow * DOUT + kc * 32 + g * 8);

    const ushort* Ks = Kbf + (size_t)p * TTP * DOUT;
    const ushort* Vt = VbfT + (size_t)p * DOUT * TTP;

    f32x4 o[8];
    #pragma unroll
    for (int i = 0; i < 8; ++i) o[i] = (f32x4){0.f, 0.f, 0.f, 0.f};
    float m = -INFINITY, l = 0.f;   // per-lane scalars: stats for q = r16

    // key-tile range for this wave: wave0 -> 9 tiles, waves1-3 -> 8 tiles
    int jt0 = (wid == 0) ? 0 : (8 * wid + 1);
    int ntl = (wid == 0) ? 9 : 8;

    for (int jj = 0; jj < ntl; ++jj) {
        int k0 = (jt0 + jj) * 32;
        f32x4 s0 = (f32x4){0.f, 0.f, 0.f, 0.f};
        f32x4 s1 = (f32x4){0.f, 0.f, 0.f, 0.f};
        __builtin_amdgcn_s_setprio(1);
        #pragma unroll
        for (int kc = 0; kc < 4; ++kc) {
            short8 kf0 = *(const short8*)(Ks + (size_t)(k0 + r16) * DOUT + kc * 32 + g * 8);
            short8 kf1 = *(const short8*)(Ks + (size_t)(k0 + 16 + r16) * DOUT + kc * 32 + g * 8);
            s0 = __builtin_amdgcn_mfma_f32_16x16x32_bf16(kf0, qf[kc], s0, 0, 0, 0);  // C[key][q]
            s1 = __builtin_amdgcn_mfma_f32_16x16x32_bf16(kf1, qf[kc], s1, 0, 0, 0);
        }
        __builtin_amdgcn_s_setprio(0);
        // lane-local softmax for q = r16 over this tile's 32 keys:
        // lane holds keys {k0+4g+r} (s0) and {k0+16+4g+r} (s1)
        float a[8];
        #pragma unroll
        for (int r = 0; r < 4; ++r) {
            a[r]     = (k0 + 4 * g + r < TT)      ? s0[r] : -INFINITY;
            a[4 + r] = (k0 + 16 + 4 * g + r < TT) ? s1[r] : -INFINITY;
        }
        float pmax = fmaxf(fmaxf(fmaxf(a[0], a[1]), fmaxf(a[2], a[3])),
                           fmaxf(fmaxf(a[4], a[5]), fmaxf(a[6], a[7])));
        pmax = fmaxf(pmax, __shfl_xor(pmax, 16));
        pmax = fmaxf(pmax, __shfl_xor(pmax, 32));
        float mn = fmaxf(m, pmax);
        float corr = __expf(m - mn);   // first tile: exp(-inf) = 0
        m = mn;
        float ps = 0.f;
        #pragma unroll
        for (int i2 = 0; i2 < 8; ++i2) { a[i2] = __expf(a[i2] - mn); ps += a[i2]; }
        ps += __shfl_xor(ps, 16);
        ps += __shfl_xor(ps, 32);
        l = l * corr + ps;
        // o accumulators live at q = 4g+r: fetch that q's corr (uniform over groups)
        float corrO[4];
        #pragma unroll
        for (int r = 0; r < 4; ++r)
            corrO[r] = __shfl(corr, (lane & 48) + 4 * g + r);
        #pragma unroll
        for (int db = 0; db < 8; ++db) {
            #pragma unroll
            for (int r = 0; r < 4; ++r) o[db][r] *= corrO[r];
        }
        // P exchange: P[k][q] regs -> Plds[q][k] -> A-operand rows
        int buf = jj & 1;   // per-wave double buffer: no WAR on in-flight reads
        #pragma unroll
        for (int r = 0; r < 4; ++r) {
            Plds[wid][buf][r16][4 * g + r]      = f2bf(a[r]);
            Plds[wid][buf][r16][16 + 4 * g + r] = f2bf(a[4 + r]);
        }
        // single-wave LDS exchange: compiler inserts lgkmcnt wait; no barrier
        short8 pa = *(const short8*)&Plds[wid][buf][r16][g * 8];
        __builtin_amdgcn_s_setprio(1);
        #pragma unroll
        for (int db = 0; db < 8; ++db) {
            short8 vf = *(const short8*)(Vt + (size_t)(db * 16 + r16) * TTP + k0 + g * 8);
            o[db] = __builtin_amdgcn_mfma_f32_16x16x32_bf16(pa, vf, o[db], 0, 0, 0);
        }
        __builtin_amdgcn_s_setprio(0);
    }

    // ---- cross-wave combine (split-K merge), 2 rounds of 64 dims ----
    if (g == 0) { mstats[wid][r16][0] = m; mstats[wid][r16][1] = l; }
    __syncthreads();
    float M = mstats[0][r16][0];
    M = fmaxf(M, mstats[1][r16][0]);
    M = fmaxf(M, mstats[2][r16][0]);
    M = fmaxf(M, mstats[3][r16][0]);
    float L = 0.f;
    #pragma unroll
    for (int w = 0; w < 4; ++w)
        L += mstats[w][r16][1] * __expf(mstats[w][r16][0] - M);
    float facinv = __expf(m - M) / L;   // per-lane, q = r16
    float facO[4];
    #pragma unroll
    for (int r = 0; r < 4; ++r)
        facO[r] = __shfl(facinv, (lane & 48) + 4 * g + r);   // to o's q = 4g+r
    #pragma unroll
    for (int rd = 0; rd < 2; ++rd) {
        __syncthreads();   // previous round's reads (and mstats reads) complete
        #pragma unroll
        for (int dh = 0; dh < 4; ++dh) {
            int db = rd * 4 + dh;
            #pragma unroll
            for (int r = 0; r < 4; ++r)
                Ocomb[wid][4 * g + r][dh * 16 + r16] = o[db][r] * facO[r];
        }
        __syncthreads();
        #pragma unroll
        for (int e = tid; e < 16 * 64; e += 256) {
            int q = e >> 6, dd = e & 63;
            int qg = q0 + q;
            if (qg < TT) {
                float s = Ocomb[0][q][dd] + Ocomb[1][q][dd] + Ocomb[2][q][dd] + Ocomb[3][q][dd];
                Obuf[((size_t)p * TT + qg) * DOUT + rd * 64 + dd] = s;
            }
        }
    }
}

// ---------------- kernel 5: proto = mean over shots ----------------
__global__ void proto_kernel(const float* __restrict__ Obuf, float* __restrict__ proto) {
    int c = blockIdx.y;
    int idx = blockIdx.x * 256 + threadIdx.x;
    if (idx >= TT * DOUT) return;
    float a = 0.f;
    #pragma unroll
    for (int s = 0; s < SHOT; ++s)
        a += Obuf[((size_t)(c * SHOT + s) * TT) * DOUT + idx];
    proto[(size_t)c * TT * DOUT + idx] = a * 0.2f;
}

// ---------------- kernel 6a: logits partial sums (parallel) ----------------
__global__ __launch_bounds__(256) void logits_partial_kernel(
        const float* __restrict__ V, const float* __restrict__ proto,
        float* __restrict__ partial) {
    int c = blockIdx.y, tid = threadIdx.x;
    const float4* qv = (const float4*)(V + (size_t)NSUP * TT * DOUT);
    const float4* pr = (const float4*)(proto + (size_t)c * TT * DOUT);
    float sum = 0.f;
    const int n4 = TT * DOUT / 4;   // 33120
    for (int i = blockIdx.x * 256 + tid; i < n4; i += LNB * 256) {
        float4 q = qv[i], p = pr[i];
        float dx = q.x - p.x, dy = q.y - p.y, dz = q.z - p.z, dw = q.w - p.w;
        sum += dx * dx + dy * dy + dz * dz + dw * dw;
    }
    for (int off = 32; off >= 1; off >>= 1) sum += __shfl_down(sum, off);
    __shared__ float red[4];
    int w = tid >> 6, lane = tid & 63;
    if (lane == 0) red[w] = sum;
    __syncthreads();
    if (tid == 0) partial[c * LNB + blockIdx.x] = red[0] + red[1] + red[2] + red[3];
}

// ---------------- kernel 6b: logits finalize ----------------
__global__ void logits_final_kernel(const float* __restrict__ partial, float* __restrict__ out) {
    int c = threadIdx.x;
    if (c < WAY) {
        float s = 0.f;
        #pragma unroll
        for (int b = 0; b < LNB; ++b) s += partial[c * LNB + b];
        out[c] = -s / (float)TT;
    }
}

// ---------------- kernel 7: argmax + is_true = exp(qv - proto[best]) ----------------
__global__ void istrue_kernel(const float* __restrict__ V, const float* __restrict__ proto,
                              float* out) {
    float l0 = out[0];
    int best = 0;
    for (int cc = 1; cc < WAY; ++cc) {
        float lc = out[cc];
        if (lc > l0) { l0 = lc; best = cc; }
    }
    const float* qv = V + (size_t)NSUP * TT * DOUT;
    const float* pr = proto + (size_t)best * TT * DOUT;
    int idx = blockIdx.x * 256 + threadIdx.x;
    if (idx < TT * DOUT) out[5 + idx] = expf(qv[idx] - pr[idx]);
}

extern "C" void kernel_launch(void* const* d_in, const int* in_sizes, int n_in,
                              void* d_out, int out_size, void* d_ws, size_t ws_size,
                              hipStream_t stream) {
    const float* ss  = (const float*)d_in[0];
    const float* qsk = (const float*)d_in[1];
    // d_in[2] = ss_labels (sorted balanced; reduces to a reshape)
    const float* w1 = (const float*)d_in[3];
    const float* b1 = (const float*)d_in[4];
    const float* w2 = (const float*)d_in[5];
    const float* b2 = (const float*)d_in[6];
    const float* kw = (const float*)d_in[7];
    const float* kb = (const float*)d_in[8];
    const float* vw = (const float*)d_in[9];
    const float* vb = (const float*)d_in[10];
    const float* lg = (const float*)d_in[11];
    const float* lb = (const float*)d_in[12];
    float* out = (float*)d_out;

    float* w = (float*)d_ws;
    float* feat = w;                                   // 1196*256 f32
    float* kp1  = feat + 1196 * 256;                   // 1196*128 f32 each
    float* kp2  = kp1 + 1196 * 128;
    float* vp1  = kp2 + 1196 * 128;
    float* vp2  = vp1 + 1196 * 128;
    float* Vb   = vp2 + 1196 * 128;                    // 26*1035*128 f32
    float* Obuf = Vb + (size_t)NSEQ * TT * DOUT;       // 25*1035*128 f32
    float* proto = Obuf + (size_t)NSUP * TT * DOUT;    // 5*1035*128 f32
    float* partial = proto + (size_t)WAY * TT * DOUT;  // WAY*LNB f32
    ushort* Kbf = (ushort*)(partial + WAY * LNB);      // 26*1056*128 u16
    ushort* VbfT = Kbf + (size_t)NSEQ * TTP * DOUT;    // 25*128*1056 u16
    // total ~47 MB

    hipLaunchKernelGGL(mlp_pe_kernel, dim3(NSEQ * LSEQ), dim3(256), 0, stream,
                       ss, qsk, w1, b1, w2, b2, feat);
    hipLaunchKernelGGL(proj_kernel, dim3(NSEQ * LSEQ), dim3(128), 0, stream,
                       feat, kw, vw, kp1, kp2, vp1, vp2);
    hipLaunchKernelGGL(kv_kernel, dim3(NSEQ * TT), dim3(128), 0, stream,
                       kp1, kp2, vp1, vp2, kb, vb, lg, lb, Kbf, Vb);
    hipLaunchKernelGGL(vtrans_kernel, dim3(33, 4, NSUP), dim3(256), 0, stream,
                       Vb, VbfT);
    hipLaunchKernelGGL(attn_mfma_kernel, dim3(65 * NSUP), dim3(256), 0, stream,
                       Kbf, VbfT, Obuf);
    hipLaunchKernelGGL(proto_kernel, dim3((TT * DOUT + 255) / 256, WAY), dim3(256), 0, stream,
                       Obuf, proto);
    hipLaunchKernelGGL(logits_partial_kernel, dim3(LNB, WAY), dim3(256), 0, stream,
                       Vb, proto, partial);
    hipLaunchKernelGGL(logits_final_kernel, dim3(1), dim3(64), 0, stream, partial, out);
    hipLaunchKernelGGL(istrue_kernel, dim3((TT * DOUT + 255) / 256), dim3(256), 0, stream,
                       Vb, proto, out);
}

// Round 9
// 159.342 us; speedup vs baseline: 1.1762x; 1.1762x over previous
//
#include <hip/hip_runtime.h>
#include <hip/hip_bf16.h>
#include <math.h>

#define NSEQ 26
#define NSUP 25
#define LSEQ 46
#define DJ 90
#define H1 180
#define DIN 256
#define TT 1035
#define TTP 1056     // padded to 33*32
#define DOUT 128
#define WAY 5
#define SHOT 5
#define LNB 32       // logits partial blocks per class
#define SQRT_SCALE 0.29730177875068026f   // (1/sqrt(128))^0.5, folded into K (Q and K both)

typedef __attribute__((ext_vector_type(8))) short short8;
typedef __attribute__((ext_vector_type(4))) float f32x4;

__device__ __forceinline__ ushort f2bf(float x) {
    __hip_bfloat16 h = __float2bfloat16(x);
    return *reinterpret_cast<ushort*>(&h);
}
__device__ __forceinline__ ushort4 pk4(float a0, float a1, float a2, float a3) {
    ushort4 u; u.x = f2bf(a0); u.y = f2bf(a1); u.z = f2bf(a2); u.w = f2bf(a3); return u;
}

// ---------------- kernel 1: MLP (two relu layers) + positional encoding ----------------
__global__ void mlp_pe_kernel(const float* __restrict__ ss, const float* __restrict__ qsk,
                              const float* __restrict__ w1, const float* __restrict__ b1,
                              const float* __restrict__ w2, const float* __restrict__ b2,
                              float* __restrict__ feat) {
    __shared__ float xs[DJ];
    __shared__ float hs[H1];
    int r = blockIdx.x;
    int seq = r / LSEQ, l = r % LSEQ;
    const float* x = (seq < NSUP) ? (ss + (size_t)(seq * LSEQ + l) * DJ)
                                  : (qsk + (size_t)l * DJ);
    int tid = threadIdx.x;
    if (tid < DJ) xs[tid] = x[tid];
    __syncthreads();
    if (tid < H1) {
        float a = b1[tid];
        for (int k = 0; k < DJ; ++k) a += xs[k] * w1[k * H1 + tid];
        hs[tid] = fmaxf(a, 0.f);
    }
    __syncthreads();
    int d = tid;  // 0..255
    float a = b2[d];
    for (int k = 0; k < H1; ++k) a += hs[k] * w2[k * DIN + d];
    a = fmaxf(a, 0.f);
    int p2 = d & ~1;
    float freq = expf((float)p2 * (-9.210340371976184f / 256.0f));
    float ang = (float)l * freq;
    a += ((d & 1) ? cosf(ang) : sinf(ang)) * 0.1f;
    feat[(size_t)r * DIN + d] = a;
}

// ---------------- kernel 2: per-frame half projections (factorized tuple GEMM) ----------------
__global__ void proj_kernel(const float* __restrict__ feat,
                            const float* __restrict__ kw, const float* __restrict__ vw,
                            float* __restrict__ kp1, float* __restrict__ kp2,
                            float* __restrict__ vp1, float* __restrict__ vp2) {
    __shared__ float fs[DIN];
    int r = blockIdx.x, d = threadIdx.x;  // 128 threads
    fs[d] = feat[(size_t)r * DIN + d];
    fs[d + 128] = feat[(size_t)r * DIN + d + 128];
    __syncthreads();
    float a1 = 0.f, a2 = 0.f, a3 = 0.f, a4 = 0.f;
    for (int k = 0; k < DIN; ++k) {
        float f = fs[k];
        a1 += f * kw[k * DOUT + d];
        a2 += f * kw[(k + DIN) * DOUT + d];
        a3 += f * vw[k * DOUT + d];
        a4 += f * vw[(k + DIN) * DOUT + d];
    }
    size_t o = (size_t)r * DOUT + d;
    kp1[o] = a1; kp2[o] = a2; vp1[o] = a3; vp2[o] = a4;
}

// ---------------- kernel 3: tuple gather + bias + LayerNorm -> Kbf(bf16, pre-scaled), V(f32) ----------------
__global__ void kv_kernel(const float* __restrict__ kp1, const float* __restrict__ kp2,
                          const float* __restrict__ vp1, const float* __restrict__ vp2,
                          const float* __restrict__ kb, const float* __restrict__ vb,
                          const float* __restrict__ lg, const float* __restrict__ lb,
                          ushort* __restrict__ Kbf, float* __restrict__ V) {
    int b = blockIdx.x;
    int s = b / TT, t = b % TT;
    int i = 0, rem = t;
    while (rem >= (LSEQ - 1 - i)) { rem -= (LSEQ - 1 - i); ++i; }
    int j = i + 1 + rem;
    int d = threadIdx.x;  // 128 threads
    size_t fi = (size_t)(s * LSEQ + i) * DOUT + d;
    size_t fj = (size_t)(s * LSEQ + j) * DOUT + d;
    float kv = kp1[fi] + kp2[fj] + kb[d];
    float vv = vp1[fi] + vp2[fj] + vb[d];
    float sum = kv, sq = kv * kv;
    for (int off = 32; off >= 1; off >>= 1) {
        sum += __shfl_down(sum, off);
        sq  += __shfl_down(sq, off);
    }
    __shared__ float red[4];
    int wid = d >> 6, lane = d & 63;
    if (lane == 0) { red[wid * 2] = sum; red[wid * 2 + 1] = sq; }
    __syncthreads();
    sum = red[0] + red[2]; sq = red[1] + red[3];
    float m = sum * (1.f / DOUT);
    float var = sq * (1.f / DOUT) - m * m;
    float rs = rsqrtf(var + 1e-5f);
    float kn = ((kv - m) * rs * lg[d] + lb[d]) * SQRT_SCALE;
    Kbf[(size_t)s * TTP * DOUT + (size_t)t * DOUT + d] = f2bf(kn);
    V[((size_t)s * TT + t) * DOUT + d] = vv;
}

// ---------------- kernel 3b: V -> bf16 transpose  VbfT[p][d][t] ----------------
__global__ void vtrans_kernel(const float* __restrict__ V, ushort* __restrict__ VbfT) {
    __shared__ float tile[32][33];
    int p = blockIdx.z;
    int t0 = blockIdx.x * 32, d0 = blockIdx.y * 32;
    int tx = threadIdx.x & 31, ty = threadIdx.x >> 5;  // 256 thr: ty 0..7
    for (int i = ty; i < 32; i += 8) {
        int t = t0 + i;
        tile[i][tx] = (t < TT) ? V[((size_t)p * TT + t) * DOUT + d0 + tx] : 0.f;
    }
    __syncthreads();
    for (int i = ty; i < 32; i += 8) {
        int d = d0 + i;
        VbfT[((size_t)p * DOUT + d) * TTP + t0 + tx] = f2bf(tile[tx][i]);
    }
}

// ---------------- kernel 4: split-K MFMA flash attention, fixed-max softmax ----------------
// Swapped QK^T (C[key][q]); softmax uses a FIXED max of 0 (valid: LayerNormed
// rows bound |S| <= sqrt(128) ~ 11.4 -> e^S <= 9e4, fp32/bf16-safe), so there
// is NO online rescale, NO per-tile cross-lane reduction, and the split-K
// combine is a plain sum of (o, l). K fragments live in registers and are
// refilled for tile jj+1 right after tile jj's QK^T consumes them (latency
// hidden under softmax+PV). No min-waves bound (round-6 spill lesson).
__global__ __launch_bounds__(256) void attn_mfma_kernel(
        const ushort* __restrict__ Kbf, const ushort* __restrict__ VbfT,
        float* __restrict__ Obuf) {
    __shared__ __align__(16) ushort Plds[4][2][16][40];  // per-wave, dbuf by tile parity
    __shared__ float Ocomb[4][16][66];                    // 2-round combine, padded rows
    __shared__ float lstats[16][4];                       // [q][wave]

    // bijective XCD-chunk swizzle (nwg=1625, nwg%8=1)
    const int nwg = 65 * NSUP;
    int orig = blockIdx.x;
    int cq = nwg >> 3, cr = nwg & 7;           // 203, 1
    int xcd = orig & 7, sub = orig >> 3;
    int wg = (xcd < cr ? xcd * (cq + 1) : cr * (cq + 1) + (xcd - cr) * cq) + sub;
    int p = wg / 65;                            // support pair 0..24
    int q0 = (wg % 65) * 16;

    int tid = threadIdx.x;
    int wid = tid >> 6;
    int lane = tid & 63;
    int g = lane >> 4, r16 = lane & 15;

    const ushort* Kq = Kbf + (size_t)NSUP * TTP * DOUT;   // query rows
    short8 qf[4];
    int qrow = q0 + r16;
    #pragma unroll
    for (int kc = 0; kc < 4; ++kc)
        qf[kc] = *(const short8*)(Kq + (size_t)qrow * DOUT + kc * 32 + g * 8);

    const ushort* Ks = Kbf + (size_t)p * TTP * DOUT;
    const ushort* Vt = VbfT + (size_t)p * DOUT * TTP;

    f32x4 o[8];
    #pragma unroll
    for (int i = 0; i < 8; ++i) o[i] = (f32x4){0.f, 0.f, 0.f, 0.f};
    float lacc = 0.f;   // per-lane partial denom (own 8 k-slots), reduced in epilogue

    // key-tile range for this wave: wave0 -> 9 tiles, waves1-3 -> 8 tiles
    int jt0 = (wid == 0) ? 0 : (8 * wid + 1);
    int ntl = (wid == 0) ? 9 : 8;

    // preload K fragments for first tile
    short8 kf[8];
    {
        int k0 = jt0 * 32;
        #pragma unroll
        for (int kc = 0; kc < 4; ++kc) {
            kf[2 * kc]     = *(const short8*)(Ks + (size_t)(k0 + r16) * DOUT + kc * 32 + g * 8);
            kf[2 * kc + 1] = *(const short8*)(Ks + (size_t)(k0 + 16 + r16) * DOUT + kc * 32 + g * 8);
        }
    }

    for (int jj = 0; jj < ntl; ++jj) {
        int k0 = (jt0 + jj) * 32;
        f32x4 s0 = (f32x4){0.f, 0.f, 0.f, 0.f};
        f32x4 s1 = (f32x4){0.f, 0.f, 0.f, 0.f};
        __builtin_amdgcn_s_setprio(1);
        #pragma unroll
        for (int kc = 0; kc < 4; ++kc) {
            s0 = __builtin_amdgcn_mfma_f32_16x16x32_bf16(kf[2 * kc],     qf[kc], s0, 0, 0, 0);
            s1 = __builtin_amdgcn_mfma_f32_16x16x32_bf16(kf[2 * kc + 1], qf[kc], s1, 0, 0, 0);
        }
        __builtin_amdgcn_s_setprio(0);
        // refill kf for the NEXT tile (issued now; consumed next iteration)
        int nk0 = (jj + 1 < ntl) ? (jt0 + jj + 1) * 32 : jt0 * 32;
        #pragma unroll
        for (int kc = 0; kc < 4; ++kc) {
            kf[2 * kc]     = *(const short8*)(Ks + (size_t)(nk0 + r16) * DOUT + kc * 32 + g * 8);
            kf[2 * kc + 1] = *(const short8*)(Ks + (size_t)(nk0 + 16 + r16) * DOUT + kc * 32 + g * 8);
        }
        // fixed-max softmax: P = exp(S), masked for padded keys
        float a[8];
        #pragma unroll
        for (int r = 0; r < 4; ++r) {
            a[r]     = (k0 + 4 * g + r < TT)      ? __expf(s0[r]) : 0.f;
            a[4 + r] = (k0 + 16 + 4 * g + r < TT) ? __expf(s1[r]) : 0.f;
        }
        lacc += ((a[0] + a[1]) + (a[2] + a[3])) + ((a[4] + a[5]) + (a[6] + a[7]));
        // P exchange: P[k][q] regs -> Plds[q][k] -> A-operand rows (2x ds_write_b64)
        int buf = jj & 1;   // per-wave double buffer: no WAR on in-flight reads
        *(ushort4*)&Plds[wid][buf][r16][4 * g]      = pk4(a[0], a[1], a[2], a[3]);
        *(ushort4*)&Plds[wid][buf][r16][16 + 4 * g] = pk4(a[4], a[5], a[6], a[7]);
        // single-wave LDS exchange: compiler inserts lgkmcnt wait; no barrier
        short8 pa = *(const short8*)&Plds[wid][buf][r16][g * 8];
        __builtin_amdgcn_s_setprio(1);
        #pragma unroll
        for (int db = 0; db < 8; ++db) {
            short8 vf = *(const short8*)(Vt + (size_t)(db * 16 + r16) * TTP + k0 + g * 8);
            o[db] = __builtin_amdgcn_mfma_f32_16x16x32_bf16(pa, vf, o[db], 0, 0, 0);
        }
        __builtin_amdgcn_s_setprio(0);
    }

    // ---- epilogue: reduce l across g-groups, then plain-sum combine ----
    lacc += __shfl_xor(lacc, 16);
    lacc += __shfl_xor(lacc, 32);          // all 4 g now hold full l for q=r16
    if (g == 0) lstats[r16][wid] = lacc;
    __syncthreads();
    float invL[4];
    #pragma unroll
    for (int r = 0; r < 4; ++r) {
        int q = 4 * g + r;                  // o rows live at q = 4g+r
        float4 lq = *(const float4*)&lstats[q][0];
        invL[r] = 1.f / (((lq.x + lq.y) + (lq.z + lq.w)));
    }
    #pragma unroll
    for (int rd = 0; rd < 2; ++rd) {
        __syncthreads();   // previous round's reads (and lstats reads) complete
        #pragma unroll
        for (int dh = 0; dh < 4; ++dh) {
            int db = rd * 4 + dh;
            #pragma unroll
            for (int r = 0; r < 4; ++r)
                Ocomb[wid][4 * g + r][dh * 16 + r16] = o[db][r] * invL[r];
        }
        __syncthreads();
        #pragma unroll
        for (int e = tid; e < 16 * 64; e += 256) {
            int q = e >> 6, dd = e & 63;
            int qg = q0 + q;
            if (qg < TT) {
                float s = Ocomb[0][q][dd] + Ocomb[1][q][dd] + Ocomb[2][q][dd] + Ocomb[3][q][dd];
                Obuf[((size_t)p * TT + qg) * DOUT + rd * 64 + dd] = s;
            }
        }
    }
}

// ---------------- kernel 5: proto = mean over shots ----------------
__global__ void proto_kernel(const float* __restrict__ Obuf, float* __restrict__ proto) {
    int c = blockIdx.y;
    int idx = blockIdx.x * 256 + threadIdx.x;
    if (idx >= TT * DOUT) return;
    float a = 0.f;
    #pragma unroll
    for (int s = 0; s < SHOT; ++s)
        a += Obuf[((size_t)(c * SHOT + s) * TT) * DOUT + idx];
    proto[(size_t)c * TT * DOUT + idx] = a * 0.2f;
}

// ---------------- kernel 6a: logits partial sums (parallel) ----------------
__global__ __launch_bounds__(256) void logits_partial_kernel(
        const float* __restrict__ V, const float* __restrict__ proto,
        float* __restrict__ partial) {
    int c = blockIdx.y, tid = threadIdx.x;
    const float4* qv = (const float4*)(V + (size_t)NSUP * TT * DOUT);
    const float4* pr = (const float4*)(proto + (size_t)c * TT * DOUT);
    float sum = 0.f;
    const int n4 = TT * DOUT / 4;   // 33120
    for (int i = blockIdx.x * 256 + tid; i < n4; i += LNB * 256) {
        float4 q = qv[i], p = pr[i];
        float dx = q.x - p.x, dy = q.y - p.y, dz = q.z - p.z, dw = q.w - p.w;
        sum += dx * dx + dy * dy + dz * dz + dw * dw;
    }
    for (int off = 32; off >= 1; off >>= 1) sum += __shfl_down(sum, off);
    __shared__ float red[4];
    int w = tid >> 6, lane = tid & 63;
    if (lane == 0) red[w] = sum;
    __syncthreads();
    if (tid == 0) partial[c * LNB + blockIdx.x] = red[0] + red[1] + red[2] + red[3];
}

// ---------------- kernel 6b: logits finalize ----------------
__global__ void logits_final_kernel(const float* __restrict__ partial, float* __restrict__ out) {
    int c = threadIdx.x;
    if (c < WAY) {
        float s = 0.f;
        #pragma unroll
        for (int b = 0; b < LNB; ++b) s += partial[c * LNB + b];
        out[c] = -s / (float)TT;
    }
}

// ---------------- kernel 7: argmax + is_true = exp(qv - proto[best]) ----------------
__global__ void istrue_kernel(const float* __restrict__ V, const float* __restrict__ proto,
                              float* out) {
    float l0 = out[0];
    int best = 0;
    for (int cc = 1; cc < WAY; ++cc) {
        float lc = out[cc];
        if (lc > l0) { l0 = lc; best = cc; }
    }
    const float* qv = V + (size_t)NSUP * TT * DOUT;
    const float* pr = proto + (size_t)best * TT * DOUT;
    int idx = blockIdx.x * 256 + threadIdx.x;
    if (idx < TT * DOUT) out[5 + idx] = expf(qv[idx] - pr[idx]);
}

extern "C" void kernel_launch(void* const* d_in, const int* in_sizes, int n_in,
                              void* d_out, int out_size, void* d_ws, size_t ws_size,
                              hipStream_t stream) {
    const float* ss  = (const float*)d_in[0];
    const float* qsk = (const float*)d_in[1];
    // d_in[2] = ss_labels (sorted balanced; reduces to a reshape)
    const float* w1 = (const float*)d_in[3];
    const float* b1 = (const float*)d_in[4];
    const float* w2 = (const float*)d_in[5];
    const float* b2 = (const float*)d_in[6];
    const float* kw = (const float*)d_in[7];
    const float* kb = (const float*)d_in[8];
    const float* vw = (const float*)d_in[9];
    const float* vb = (const float*)d_in[10];
    const float* lg = (const float*)d_in[11];
    const float* lb = (const float*)d_in[12];
    float* out = (float*)d_out;

    float* w = (float*)d_ws;
    float* feat = w;                                   // 1196*256 f32
    float* kp1  = feat + 1196 * 256;                   // 1196*128 f32 each
    float* kp2  = kp1 + 1196 * 128;
    float* vp1  = kp2 + 1196 * 128;
    float* vp2  = vp1 + 1196 * 128;
    float* Vb   = vp2 + 1196 * 128;                    // 26*1035*128 f32
    float* Obuf = Vb + (size_t)NSEQ * TT * DOUT;       // 25*1035*128 f32
    float* proto = Obuf + (size_t)NSUP * TT * DOUT;    // 5*1035*128 f32
    float* partial = proto + (size_t)WAY * TT * DOUT;  // WAY*LNB f32
    ushort* Kbf = (ushort*)(partial + WAY * LNB);      // 26*1056*128 u16
    ushort* VbfT = Kbf + (size_t)NSEQ * TTP * DOUT;    // 25*128*1056 u16
    // total ~47 MB

    hipLaunchKernelGGL(mlp_pe_kernel, dim3(NSEQ * LSEQ), dim3(256), 0, stream,
                       ss, qsk, w1, b1, w2, b2, feat);
    hipLaunchKernelGGL(proj_kernel, dim3(NSEQ * LSEQ), dim3(128), 0, stream,
                       feat, kw, vw, kp1, kp2, vp1, vp2);
    hipLaunchKernelGGL(kv_kernel, dim3(NSEQ * TT), dim3(128), 0, stream,
                       kp1, kp2, vp1, vp2, kb, vb, lg, lb, Kbf, Vb);
    hipLaunchKernelGGL(vtrans_kernel, dim3(33, 4, NSUP), dim3(256), 0, stream,
                       Vb, VbfT);
    hipLaunchKernelGGL(attn_mfma_kernel, dim3(65 * NSUP), dim3(256), 0, stream,
                       Kbf, VbfT, Obuf);
    hipLaunchKernelGGL(proto_kernel, dim3((TT * DOUT + 255) / 256, WAY), dim3(256), 0, stream,
                       Obuf, proto);
    hipLaunchKernelGGL(logits_partial_kernel, dim3(LNB, WAY), dim3(256), 0, stream,
                       Vb, proto, partial);
    hipLaunchKernelGGL(logits_final_kernel, dim3(1), dim3(64), 0, stream, partial, out);
    hipLaunchKernelGGL(istrue_kernel, dim3((TT * DOUT + 255) / 256), dim3(256), 0, stream,
                       Vb, proto, out);
}